// Round 1
// baseline (18.046 us; speedup 1.0000x reference)
//
#include <hip/hip_runtime.h>
#include <hip/hip_bf16.h>

// Problem: B=4096, D=512, K=64
//   G[d,k] = sum_f F[d,f] * W[f,k]            (512x64, precomputed in ws)
//   X[b,d] = obs[b,d] * mask[b,d]
//   s0[b]  = sum_d mask[b,d]
//   s1[b]  = sum_d mask[b,d] * bvec[d]
//   out[b,k] = relu( X[b,:]·G[:,k] + s1[b]*W[10,k] + s0[b]*bw[k] )

#define D_DIM 512
#define K_DIM 64
#define B_DIM 4096

__global__ void prep_G_kernel(const float* __restrict__ F,
                              const float* __restrict__ W,
                              float* __restrict__ G) {
    int i = blockIdx.x * blockDim.x + threadIdx.x;   // 0 .. 512*64-1
    int d = i >> 6;
    int k = i & 63;
    float s = 0.f;
#pragma unroll
    for (int f = 0; f < 10; ++f)
        s = fmaf(F[d * 10 + f], W[f * 64 + k], s);
    G[i] = s;
}

__global__ __launch_bounds__(512, 2)
void main_kernel(const float* __restrict__ obs,
                 const float* __restrict__ mask,
                 const float* __restrict__ bvec,
                 const float* __restrict__ W,
                 const float* __restrict__ bw,
                 const float* __restrict__ G,
                 float* __restrict__ out) {
    __shared__ float Xs[8][D_DIM];        // 16 KB: X rows for this block
    __shared__ float part[8][8][K_DIM];   // 16 KB: [row][wave][k] partials
    __shared__ float s0s[8], s1s[8];

    const int tid = threadIdx.x;
    const int w   = tid >> 6;    // wave 0..7
    const int l   = tid & 63;    // lane = k
    const int rowbase = blockIdx.x * 8;

    // ---- prologue: wave w holds G[dbase .. dbase+63][l] in registers ----
    const int dbase = w * 64;
    float g[64];
#pragma unroll
    for (int j = 0; j < 64; ++j)
        g[j] = G[(dbase + j) * K_DIM + l];

    // bvec chunks (for s1 of row w, over all d = l + 64j)
    float bvj[8];
#pragma unroll
    for (int j = 0; j < 8; ++j)
        bvj[j] = bvec[l + 64 * j];

    // epilogue constants per lane
    const float w10 = W[10 * K_DIM + l];
    const float bwv = bw[l];

    // ---- stage: wave w loads row (rowbase+w), computes X, s0, s1 ----
    {
        const int row = rowbase + w;
        const float* orow = obs  + (size_t)row * D_DIM;
        const float* mrow = mask + (size_t)row * D_DIM;
        float p0 = 0.f, p1 = 0.f;
#pragma unroll
        for (int j = 0; j < 8; ++j) {
            int d = l + 64 * j;
            float o = orow[d];
            float m = mrow[d];
            Xs[w][d] = o * m;
            p0 += m;
            p1 = fmaf(m, bvj[j], p1);
        }
#pragma unroll
        for (int s = 1; s < 64; s <<= 1) {
            p0 += __shfl_xor(p0, s, 64);
            p1 += __shfl_xor(p1, s, 64);
        }
        if (l == 0) { s0s[w] = p0; s1s[w] = p1; }
    }
    __syncthreads();

    // ---- FMA phase: acc[r] = sum over this wave's d-slice of X[r][d]*G[d][l]
    float acc[8];
#pragma unroll
    for (int r = 0; r < 8; ++r) acc[r] = 0.f;

#pragma unroll
    for (int j = 0; j < 64; j += 4) {
#pragma unroll
        for (int r = 0; r < 8; ++r) {
            float4 xv = *reinterpret_cast<const float4*>(&Xs[r][dbase + j]);
            acc[r] = fmaf(xv.x, g[j + 0], acc[r]);
            acc[r] = fmaf(xv.y, g[j + 1], acc[r]);
            acc[r] = fmaf(xv.z, g[j + 2], acc[r]);
            acc[r] = fmaf(xv.w, g[j + 3], acc[r]);
        }
    }

    // ---- combine partials across waves ----
#pragma unroll
    for (int r = 0; r < 8; ++r) part[r][w][l] = acc[r];
    __syncthreads();

    // thread (w,l) finishes output (rowbase+w, l)
    float total = 0.f;
#pragma unroll
    for (int ww = 0; ww < 8; ++ww) total += part[w][ww][l];
    total = fmaf(s1s[w], w10, total);
    total = fmaf(s0s[w], bwv, total);
    out[(size_t)(rowbase + w) * K_DIM + l] = fmaxf(total, 0.f);
}

extern "C" void kernel_launch(void* const* d_in, const int* in_sizes, int n_in,
                              void* d_out, int out_size, void* d_ws, size_t ws_size,
                              hipStream_t stream) {
    const float* obs  = (const float*)d_in[0];  // [4096, 512]
    const float* mask = (const float*)d_in[1];  // [4096, 512]
    const float* F    = (const float*)d_in[2];  // [1, 512, 10]
    const float* bvec = (const float*)d_in[3];  // [1, 512, 1]
    const float* W    = (const float*)d_in[4];  // [11, 64]
    const float* bw   = (const float*)d_in[5];  // [64]
    float* out = (float*)d_out;                 // [4096, 64]
    float* G   = (float*)d_ws;                  // [512, 64]

    // G = F @ W[0:10]
    prep_G_kernel<<<(D_DIM * K_DIM) / 256, 256, 0, stream>>>(F, W, G);

    // main: 512 blocks x 512 threads, 8 rows per block
    main_kernel<<<B_DIM / 8, 512, 0, stream>>>(obs, mask, bvec, W, bw, G, out);
}